// Round 7
// baseline (1027.205 us; speedup 1.0000x reference)
//
#include <hip/hip_runtime.h>
#include <cstdint>
#include <cstddef>

#define NLAYERS 19
#define NB 4
#define RES_C 128
#define DIL2 256
#define SKIPC 256
#define INC 60
#define CONDC 80
#define OUTC 240
#define T_IN 6144
#define T0LEN 6135   // after start conv (K=10, VALID)
#define T_FIN 4601
#define TILE 64      // start/final tile
#define LTILE 16     // layer tile (R7: 16 -> grid ~1536, 2 dispatch rounds)
#define BLK 512

#define NDIL (NLAYERS*256*256)
#define NSKP (NLAYERS*256*128)
#define NRES (NLAYERS*128*128)
#define NEND (256*256)
#define NSTART (10*128*64)

typedef short bf16x8 __attribute__((ext_vector_type(8)));
typedef float f32x4 __attribute__((ext_vector_type(4)));
typedef unsigned uint32x2 __attribute__((ext_vector_type(2)));

#if __has_builtin(__builtin_amdgcn_exp2f)
#define EXP2F(x) __builtin_amdgcn_exp2f(x)
#else
#define EXP2F(x) exp2f(x)
#endif
#if __has_builtin(__builtin_amdgcn_rcpf)
#define RCPF(x) __builtin_amdgcn_rcpf(x)
#else
#define RCPF(x) (1.0f/(x))
#endif

__device__ __forceinline__ float fexp(float x){ return EXP2F(x * 1.4426950408889634f); }
__device__ __forceinline__ float fsigmoid(float x){ return RCPF(1.0f + fexp(-x)); }
__device__ __forceinline__ float ftanh(float x){ return 1.0f - 2.0f * RCPF(1.0f + fexp(2.0f*x)); }

__device__ __forceinline__ unsigned short f2bf(float f){
  unsigned u = __builtin_bit_cast(unsigned, f);
  u = u + 0x7FFFu + ((u >> 16) & 1u);   // RNE (finite values only)
  return (unsigned short)(u >> 16);
}

// ---------------------------------------------------------------------------
// Pack weights to bf16. dilWb rows interleaved: m even=filter ch m/2, m odd=gate ch m/2.
// K order: k<128 -> tap0 (x[t]) channel k ; k>=128 -> tap1 (x[t+d]) channel k-128.
// startWb: [tap k][oc:128][c:64 (60 used)]
__global__ void prep_weights(const float* __restrict__ dil_w, const float* __restrict__ skip_w,
                             const float* __restrict__ res_w, const float* __restrict__ end_w,
                             const float* __restrict__ start_w,
                             unsigned short* __restrict__ dilWb, unsigned short* __restrict__ skipWb,
                             unsigned short* __restrict__ resWb, unsigned short* __restrict__ endWb,
                             unsigned short* __restrict__ startWb){
  const int total = NDIL + NSKP + NRES + NEND + NSTART;
  for (int idx = blockIdx.x*256 + threadIdx.x; idx < total; idx += gridDim.x*256){
    if (idx < NDIL){
      int l = idx >> 16; int rem = idx & 65535; int m = rem >> 8; int k = rem & 255;
      int o = ((m & 1) << 7) + (m >> 1); int c = k & 127; int tap = k >> 7;
      dilWb[idx] = f2bf(dil_w[(((size_t)l*256 + o)*128 + c)*2 + tap]);
    } else if (idx < NDIL + NSKP){
      int j = idx - NDIL;
      skipWb[j] = f2bf(skip_w[j]);           // [l][m][k] identical layout
    } else if (idx < NDIL + NSKP + NRES){
      int j = idx - NDIL - NSKP;
      resWb[j] = f2bf(res_w[j]);             // [l][m][k] identical layout
    } else if (idx < NDIL + NSKP + NRES + NEND){
      int j = idx - NDIL - NSKP - NRES;
      int m = j >> 8; int k = j & 255;
      endWb[j] = (m < OUTC) ? f2bf(end_w[(size_t)m*256 + k]) : 0;
    } else {
      int j = idx - NDIL - NSKP - NRES - NEND;
      int k = j >> 13; int rem = j & 8191; int oc = rem >> 6; int c = rem & 63;
      startWb[j] = (c < INC) ? f2bf(start_w[((size_t)oc*INC + c)*10 + k]) : 0;
    }
  }
}

// ---------------------------------------------------------------------------
// cbias[l][b][m] = dil_b[o(m)] + cond_b[l][o(m)] + sum_c cond_w[l][o(m)][c]*cond[b][c]
// cend[b][o]    = cend_b[o]    + sum_c cend_w[o][c]   * cond[b][c]
__global__ void prep_bias(const float* __restrict__ cond, const float* __restrict__ dil_b,
                          const float* __restrict__ cond_w, const float* __restrict__ cond_b,
                          const float* __restrict__ cend_w, const float* __restrict__ cend_b,
                          float* __restrict__ cbias, float* __restrict__ cend){
  int blk = blockIdx.x; int m = threadIdx.x;
  if (blk < NLAYERS*NB){
    int l = blk >> 2, b = blk & 3;
    int o = ((m & 1) << 7) + (m >> 1);
    float acc = dil_b[l*256 + o] + cond_b[l*256 + o];
    const float* w = cond_w + ((size_t)l*256 + o)*CONDC;
    const float* cv = cond + b*CONDC;
    for (int c = 0; c < CONDC; ++c) acc += w[c]*cv[c];
    cbias[((size_t)l*NB + b)*256 + m] = acc;
  } else {
    int b = blk - NLAYERS*NB;
    float acc = cend_b[m];
    const float* w = cend_w + (size_t)m*CONDC;
    const float* cv = cond + b*CONDC;
    for (int c = 0; c < CONDC; ++c) acc += w[c]*cv[c];
    cend[b*256 + m] = acc;
  }
}

// ---------------------------------------------------------------------------
// start conv via MFMA, tap-decomposed: out[oc][t] = b[oc] + sum_k Wk @ in[:, t+k]
__global__ __launch_bounds__(BLK) void start_mfma(const float* __restrict__ in,
    const unsigned short* __restrict__ startWb, const float* __restrict__ bias,
    float* __restrict__ xout){
  __shared__ char Bs[80*128];   // [tt:80][c:64] bf16, 16B slots: slot ^= (tt&7)
  const int tid = threadIdx.x;
  const int b = blockIdx.y; const int t0 = blockIdx.x * TILE;
  const int lane = tid & 63;
  const int wave = __builtin_amdgcn_readfirstlane(tid >> 6);
  const int q = lane >> 4, r16 = lane & 15;

  #pragma unroll
  for (int i = 0; i < 5; ++i){
    int j = tid + i*BLK;              // 0..2559 = 32 c-pairs x 80 tt
    int c2 = j / 80, tt = j % 80;
    int c = 2*c2; int gt = t0 + tt;
    float v0 = 0.f, v1 = 0.f;
    if (gt < T_IN && c < INC){
      const float* base = in + ((size_t)(b*INC + c))*T_IN + gt;
      v0 = base[0]; v1 = base[T_IN];
    }
    unsigned u = (unsigned)f2bf(v0) | ((unsigned)f2bf(v1) << 16);
    int slot = c2 >> 2;
    *(unsigned*)(Bs + tt*128 + ((((slot ^ (tt & 7)) << 4)) | ((4*c2) & 15))) = u;
  }
  __syncthreads();

  f32x4 acc[4] = {};
  for (int k = 0; k < 10; ++k){
    const unsigned short* A = startWb + ((size_t)k*128 + wave*16)*64;
    #pragma unroll
    for (int kk = 0; kk < 2; ++kk){
      int k0 = kk*32 + q*8;
      bf16x8 a = *(const bf16x8*)(A + (size_t)r16*64 + k0);
      int slot = k0 >> 3;
      #pragma unroll
      for (int nt = 0; nt < 4; ++nt){
        int t = nt*16 + r16 + k;
        bf16x8 bf = *(const bf16x8*)(Bs + t*128 + ((slot ^ (t & 7)) << 4));
        acc[nt] = __builtin_amdgcn_mfma_f32_16x16x32_bf16(a, bf, acc[nt], 0, 0, 0);
      }
    }
  }
  const float* bb = bias + wave*16;
  #pragma unroll
  for (int nt = 0; nt < 4; ++nt){
    int gt = t0 + nt*16 + r16;
    if (gt < T0LEN){
      #pragma unroll
      for (int rr = 0; rr < 4; ++rr){
        int oc = wave*16 + 4*q + rr;
        xout[(size_t)(b*RES_C + oc)*T_IN + gt] = acc[nt][rr] + bb[4*q + rr];
      }
    }
  }
}

// ---------------------------------------------------------------------------
// Fused MFMA layer, LTILE=16, with early-issued skip-old reads (T14):
// the skip RMW read is issued at kernel top (same thread owns the same (m,tw)
// it rewrites at the end -> no hazard), so its HBM latency hides under
// stage + dil GEMM + gate + skip GEMM.
__global__ __launch_bounds__(BLK) void layer_mfma(
    const float* __restrict__ xin, float* __restrict__ xout, float* __restrict__ skip,
    const unsigned short* __restrict__ dilWb, const unsigned short* __restrict__ skipWb,
    const unsigned short* __restrict__ resWb, const float* __restrict__ cbias,
    const float* __restrict__ skip_b, const float* __restrict__ res_b,
    int layer, int d, int Tin, int Tout, int first, int last){
  __shared__ char Bx[LTILE*512];   // [t][k:256] bf16, 16B slots swizzled: slot ^= t
  __shared__ char Bz[LTILE*256];   // [t][ch:128] bf16, slot ^= t
  const int tid = threadIdx.x;
  const int b = blockIdx.y; const int t0 = blockIdx.x*LTILE;
  const int lane = tid & 63;
  const int wave = __builtin_amdgcn_readfirstlane(tid >> 6);
  const int q = lane >> 4;          // 0..3
  const int r16 = lane & 15;        // row-in-Afrag / col-in-Bfrag / local t

  // ---- early-issue old-skip reads (hidden under all compute below)
  const int gtc = t0 + r16;         // this lane's output column
  const int woff = Tout - T_FIN;
  const int tw = gtc - woff;
  const bool sval = (gtc < Tout) && (tw >= 0);
  float sold[8];
  if (!first && sval){
    #pragma unroll
    for (int mt = 0; mt < 2; ++mt){
      #pragma unroll
      for (int rr = 0; rr < 4; ++rr){
        int m = wave*32 + mt*16 + 4*q + rr;
        sold[mt*4 + rr] = skip[((size_t)(b*SKIPC + m))*T_FIN + tw];
      }
    }
  }

  // ---- stage Bx: k<128 = x[t] ch k ; k>=128 = x[t+d] ch k-128
  // 64 lanes = 16 t-values x 4 k-quarters; wave covers 32 k-channels.
  {
    const int t = lane & 15;
    const int kq = lane >> 4;       // 0..3
    const int gt = t0 + t;
    #pragma unroll
    for (int i = 0; i < 8; i += 2){
      int k0 = wave*32 + kq*8 + i;
      int tap = k0 >> 7; int c = k0 & 127;
      int gtt = gt + (tap ? d : 0);
      float v0 = 0.f, v1 = 0.f;
      if (gtt < Tin){
        const float* base = xin + ((size_t)(b*RES_C + c))*T_IN + gtt;
        v0 = base[0]; v1 = base[T_IN];
      }
      unsigned u = (unsigned)f2bf(v0) | ((unsigned)f2bf(v1) << 16);
      int slot = k0 >> 3;
      *(unsigned*)(Bx + t*512 + ((slot ^ t) << 4) + ((2*k0) & 15)) = u;
    }
  }
  __syncthreads();

  // ---- dilated GEMM: M=256 (f/g interleaved), K=256, N=16. wave owns 32 rows.
  f32x4 acc[2] = {};
  {
    const unsigned short* A = dilWb + (size_t)layer*256*256 + (size_t)(wave*32)*256;
    #pragma unroll 2
    for (int kk = 0; kk < 8; ++kk){
      int k0 = kk*32 + q*8;
      bf16x8 a0 = *(const bf16x8*)(A + (size_t)r16*256 + k0);
      bf16x8 a1 = *(const bf16x8*)(A + (size_t)(16 + r16)*256 + k0);
      int slot = k0 >> 3;
      bf16x8 bf = *(const bf16x8*)(Bx + r16*512 + ((slot ^ r16) << 4));
      acc[0] = __builtin_amdgcn_mfma_f32_16x16x32_bf16(a0, bf, acc[0], 0, 0, 0);
      acc[1] = __builtin_amdgcn_mfma_f32_16x16x32_bf16(a1, bf, acc[1], 0, 0, 0);
    }
  }

  // ---- gate + write z to Bz (rows 4q+r hold f,g,f,g of channels 2q,2q+1)
  {
    const float* cb = cbias + ((size_t)layer*NB + b)*256 + wave*32;
    #pragma unroll
    for (int mt = 0; mt < 2; ++mt){
      float bf0 = cb[mt*16 + 4*q + 0];
      float bg0 = cb[mt*16 + 4*q + 1];
      float bf1 = cb[mt*16 + 4*q + 2];
      float bg1 = cb[mt*16 + 4*q + 3];
      int ch0 = wave*16 + mt*8 + 2*q;
      int slot = ch0 >> 3;
      float z0 = ftanh(acc[mt][0] + bf0) * fsigmoid(acc[mt][1] + bg0);
      float z1 = ftanh(acc[mt][2] + bf1) * fsigmoid(acc[mt][3] + bg1);
      unsigned u = (unsigned)f2bf(z0) | ((unsigned)f2bf(z1) << 16);
      *(unsigned*)(Bz + r16*256 + ((slot ^ r16) << 4) + ((2*ch0) & 15)) = u;
    }
  }
  __syncthreads();

  // ---- skip GEMM: M=256, K=128. wave owns 32 rows. Pure write (old value preloaded).
  {
    f32x4 sacc[2] = {};
    const unsigned short* A = skipWb + (size_t)layer*256*128 + (size_t)(wave*32)*128;
    #pragma unroll
    for (int kk = 0; kk < 4; ++kk){
      int k0 = kk*32 + q*8;
      bf16x8 a0 = *(const bf16x8*)(A + (size_t)r16*128 + k0);
      bf16x8 a1 = *(const bf16x8*)(A + (size_t)(16 + r16)*128 + k0);
      int slot = k0 >> 3;
      bf16x8 bf = *(const bf16x8*)(Bz + r16*256 + ((slot ^ r16) << 4));
      sacc[0] = __builtin_amdgcn_mfma_f32_16x16x32_bf16(a0, bf, sacc[0], 0, 0, 0);
      sacc[1] = __builtin_amdgcn_mfma_f32_16x16x32_bf16(a1, bf, sacc[1], 0, 0, 0);
    }
    const float* sb = skip_b + layer*256 + wave*32;
    if (sval){
      #pragma unroll
      for (int mt = 0; mt < 2; ++mt){
        #pragma unroll
        for (int rr = 0; rr < 4; ++rr){
          int m = wave*32 + mt*16 + 4*q + rr;
          size_t si = ((size_t)(b*SKIPC + m))*T_FIN + tw;
          float v = sacc[mt][rr] + sb[mt*16 + 4*q + rr];
          skip[si] = first ? v : (v + sold[mt*4 + rr]);
        }
      }
    }
  }

  // ---- res GEMM: M=128, K=128. wave owns 16 rows. (skipped on last layer)
  if (!last){
    f32x4 racc = {};
    const unsigned short* A = resWb + (size_t)layer*128*128 + (size_t)(wave*16)*128;
    #pragma unroll
    for (int kk = 0; kk < 4; ++kk){
      int k0 = kk*32 + q*8;
      bf16x8 a0 = *(const bf16x8*)(A + (size_t)r16*128 + k0);
      int slot = k0 >> 3;
      bf16x8 bf = *(const bf16x8*)(Bz + r16*256 + ((slot ^ r16) << 4));
      racc = __builtin_amdgcn_mfma_f32_16x16x32_bf16(a0, bf, racc, 0, 0, 0);
    }
    const float* rb = res_b + layer*RES_C + wave*16;
    if (gtc < Tout){
      #pragma unroll
      for (int rr = 0; rr < 4; ++rr){
        int m = wave*16 + 4*q + rr;
        size_t base = ((size_t)(b*RES_C + m))*T_IN;
        xout[base + gtc] = racc[rr] + rb[4*q + rr] + xin[base + gtc + d];
      }
    }
  }
}

// ---------------------------------------------------------------------------
// final (proven): out = sigmoid(end_b + endW @ tanh(skip + cend)), M=240(pad 256), K=256
__global__ __launch_bounds__(BLK) void final_mfma(const float* __restrict__ skip,
    const float* __restrict__ cend, const unsigned short* __restrict__ endWb,
    const float* __restrict__ end_b, float* __restrict__ out){
  __shared__ char Bs[64*512];   // [t][s:256] bf16, slot ^= (t&31)
  const int tid = threadIdx.x;
  const int b = blockIdx.y; const int t0 = blockIdx.x*TILE;
  const int lane = tid & 63;
  const int wave = __builtin_amdgcn_readfirstlane(tid >> 6);
  const int q = lane >> 4;
  const int r16 = lane & 15;

  {
    const int t = lane;
    const int gt = t0 + t;
    #pragma unroll
    for (int i = 0; i < 32; i += 2){
      int s0 = wave*32 + i;
      float v0 = 0.f, v1 = 0.f;
      if (gt < T_FIN){
        const float* base = skip + ((size_t)(b*SKIPC + s0))*T_FIN + gt;
        v0 = ftanh(base[0]     + cend[b*256 + s0]);
        v1 = ftanh(base[T_FIN] + cend[b*256 + s0 + 1]);
      }
      unsigned u = (unsigned)f2bf(v0) | ((unsigned)f2bf(v1) << 16);
      int slot = s0 >> 3;
      *(unsigned*)(Bs + t*512 + ((slot ^ (t & 31)) << 4) + ((2*s0) & 15)) = u;
    }
  }
  __syncthreads();

  f32x4 acc[2][4] = {};
  const unsigned short* A = endWb + (size_t)(wave*32)*256;
  for (int kk = 0; kk < 8; ++kk){
    int k0 = kk*32 + q*8;
    bf16x8 a0 = *(const bf16x8*)(A + (size_t)r16*256 + k0);
    bf16x8 a1 = *(const bf16x8*)(A + (size_t)(16 + r16)*256 + k0);
    int slot = k0 >> 3;
    #pragma unroll
    for (int nt = 0; nt < 4; ++nt){
      int t = nt*16 + r16;
      bf16x8 bf = *(const bf16x8*)(Bs + t*512 + ((slot ^ (t & 31)) << 4));
      acc[0][nt] = __builtin_amdgcn_mfma_f32_16x16x32_bf16(a0, bf, acc[0][nt], 0, 0, 0);
      acc[1][nt] = __builtin_amdgcn_mfma_f32_16x16x32_bf16(a1, bf, acc[1][nt], 0, 0, 0);
    }
  }
  #pragma unroll
  for (int mt = 0; mt < 2; ++mt){
    #pragma unroll
    for (int nt = 0; nt < 4; ++nt){
      int gt = t0 + nt*16 + r16;
      if (gt < T_FIN){
        #pragma unroll
        for (int rr = 0; rr < 4; ++rr){
          int m = wave*32 + mt*16 + 4*q + rr;
          if (m < OUTC)
            out[((size_t)(b*OUTC + m))*T_FIN + gt] = fsigmoid(acc[mt][nt][rr] + end_b[m]);
        }
      }
    }
  }
}

// ---------------------------------------------------------------------------
extern "C" void kernel_launch(void* const* d_in, const int* in_sizes, int n_in,
                              void* d_out, int out_size, void* d_ws, size_t ws_size,
                              hipStream_t stream){
  const float* input     = (const float*)d_in[0];
  const float* condition = (const float*)d_in[1];
  const float* start_w   = (const float*)d_in[2];
  const float* start_b   = (const float*)d_in[3];
  const float* dil_w     = (const float*)d_in[4];
  const float* dil_b     = (const float*)d_in[5];
  const float* cond_w    = (const float*)d_in[6];
  const float* cond_b    = (const float*)d_in[7];
  const float* res_w     = (const float*)d_in[8];
  const float* res_b     = (const float*)d_in[9];
  const float* skip_w    = (const float*)d_in[10];
  const float* skip_b    = (const float*)d_in[11];
  const float* end_w     = (const float*)d_in[12];
  const float* end_b     = (const float*)d_in[13];
  const float* cend_w    = (const float*)d_in[14];
  const float* cend_b    = (const float*)d_in[15];
  float* out = (float*)d_out;

  char* ws = (char*)d_ws;
  size_t off = 0;
  auto carve = [&](size_t bytes) -> char* {
    char* p = ws + off; off = (off + bytes + 255) & ~(size_t)255; return p;
  };
  float* xA   = (float*)carve((size_t)NB*RES_C*T_IN*4);
  float* xB   = (float*)carve((size_t)NB*RES_C*T_IN*4);
  float* skip = (float*)carve((size_t)NB*SKIPC*T_FIN*4);
  unsigned short* dilWb   = (unsigned short*)carve((size_t)NDIL*2);
  unsigned short* skipWb  = (unsigned short*)carve((size_t)NSKP*2);
  unsigned short* resWb   = (unsigned short*)carve((size_t)NRES*2);
  unsigned short* endWb   = (unsigned short*)carve((size_t)NEND*2);
  unsigned short* startWb = (unsigned short*)carve((size_t)NSTART*2);
  float* cbias = (float*)carve((size_t)NLAYERS*NB*256*4);
  float* cend  = (float*)carve((size_t)NB*256*4);

  prep_weights<<<2048, 256, 0, stream>>>(dil_w, skip_w, res_w, end_w, start_w,
                                         dilWb, skipWb, resWb, endWb, startWb);
  prep_bias<<<NLAYERS*NB + NB, 256, 0, stream>>>(condition, dil_b, cond_w, cond_b,
                                                 cend_w, cend_b, cbias, cend);

  {
    dim3 grid((T0LEN + TILE - 1)/TILE, NB);
    start_mfma<<<grid, BLK, 0, stream>>>(input, startWb, start_b, xA);
  }

  int dils[NLAYERS]; int n = 0;
  for (int bb = 0; bb < 2; ++bb){ int nn = (bb==0) ? 10 : 9; for (int k = 0; k < nn; ++k) dils[n++] = 1<<k; }

  float* xin = xA; float* xo = xB;
  int Tin = T0LEN;
  for (int i = 0; i < NLAYERS; ++i){
    int d = dils[i]; int Tout = Tin - d;
    dim3 grid((Tout + LTILE - 1)/LTILE, NB);
    layer_mfma<<<grid, BLK, 0, stream>>>(xin, xo, skip, dilWb, skipWb, resWb, cbias,
                                         skip_b, res_b, i, d, Tin, Tout,
                                         (i==0)?1:0, (i==NLAYERS-1)?1:0);
    float* tmp = xin; xin = xo; xo = tmp;
    Tin = Tout;
  }

  {
    dim3 grid((T_FIN + TILE - 1)/TILE, NB);
    final_mfma<<<grid, BLK, 0, stream>>>(skip, cend, endWb, end_b, out);
  }
}

// Round 8
// 1017.391 us; speedup vs baseline: 1.0096x; 1.0096x over previous
//
#include <hip/hip_runtime.h>
#include <cstdint>
#include <cstddef>

#define NLAYERS 19
#define NB 4
#define RES_C 128
#define DIL2 256
#define SKIPC 256
#define INC 60
#define CONDC 80
#define OUTC 240
#define T_IN 6144
#define T0LEN 6135   // after start conv (K=10, VALID)
#define T_FIN 4601
#define TILE 64      // start/final tile
#define BLK 512

#define NDIL (NLAYERS*256*256)
#define NSKP (NLAYERS*256*128)
#define NRES (NLAYERS*128*128)
#define NEND (256*256)
#define NSTART (10*128*64)

typedef short bf16x8 __attribute__((ext_vector_type(8)));
typedef float f32x4 __attribute__((ext_vector_type(4)));

#if __has_builtin(__builtin_amdgcn_exp2f)
#define EXP2F(x) __builtin_amdgcn_exp2f(x)
#else
#define EXP2F(x) exp2f(x)
#endif
#if __has_builtin(__builtin_amdgcn_rcpf)
#define RCPF(x) __builtin_amdgcn_rcpf(x)
#else
#define RCPF(x) (1.0f/(x))
#endif

__device__ __forceinline__ float fexp(float x){ return EXP2F(x * 1.4426950408889634f); }
__device__ __forceinline__ float fsigmoid(float x){ return RCPF(1.0f + fexp(-x)); }
__device__ __forceinline__ float ftanh(float x){ return 1.0f - 2.0f * RCPF(1.0f + fexp(2.0f*x)); }

__device__ __forceinline__ unsigned short f2bf(float f){
  unsigned u = __builtin_bit_cast(unsigned, f);
  u = u + 0x7FFFu + ((u >> 16) & 1u);   // RNE (finite values only)
  return (unsigned short)(u >> 16);
}

// ---------------------------------------------------------------------------
// Pack weights to bf16. dilWb rows interleaved: m even=filter ch m/2, m odd=gate ch m/2.
// K order: k<128 -> tap0 (x[t]) channel k ; k>=128 -> tap1 (x[t+d]) channel k-128.
// startWb: [tap k][oc:128][c:64 (60 used)]
__global__ void prep_weights(const float* __restrict__ dil_w, const float* __restrict__ skip_w,
                             const float* __restrict__ res_w, const float* __restrict__ end_w,
                             const float* __restrict__ start_w,
                             unsigned short* __restrict__ dilWb, unsigned short* __restrict__ skipWb,
                             unsigned short* __restrict__ resWb, unsigned short* __restrict__ endWb,
                             unsigned short* __restrict__ startWb){
  const int total = NDIL + NSKP + NRES + NEND + NSTART;
  for (int idx = blockIdx.x*256 + threadIdx.x; idx < total; idx += gridDim.x*256){
    if (idx < NDIL){
      int l = idx >> 16; int rem = idx & 65535; int m = rem >> 8; int k = rem & 255;
      int o = ((m & 1) << 7) + (m >> 1); int c = k & 127; int tap = k >> 7;
      dilWb[idx] = f2bf(dil_w[(((size_t)l*256 + o)*128 + c)*2 + tap]);
    } else if (idx < NDIL + NSKP){
      int j = idx - NDIL;
      skipWb[j] = f2bf(skip_w[j]);           // [l][m][k] identical layout
    } else if (idx < NDIL + NSKP + NRES){
      int j = idx - NDIL - NSKP;
      resWb[j] = f2bf(res_w[j]);             // [l][m][k] identical layout
    } else if (idx < NDIL + NSKP + NRES + NEND){
      int j = idx - NDIL - NSKP - NRES;
      int m = j >> 8; int k = j & 255;
      endWb[j] = (m < OUTC) ? f2bf(end_w[(size_t)m*256 + k]) : 0;
    } else {
      int j = idx - NDIL - NSKP - NRES - NEND;
      int k = j >> 13; int rem = j & 8191; int oc = rem >> 6; int c = rem & 63;
      startWb[j] = (c < INC) ? f2bf(start_w[((size_t)oc*INC + c)*10 + k]) : 0;
    }
  }
}

// ---------------------------------------------------------------------------
// cbias[l][b][m] = dil_b[o(m)] + cond_b[l][o(m)] + sum_c cond_w[l][o(m)][c]*cond[b][c]
// cend[b][o]    = cend_b[o]    + sum_c cend_w[o][c]   * cond[b][c]
__global__ void prep_bias(const float* __restrict__ cond, const float* __restrict__ dil_b,
                          const float* __restrict__ cond_w, const float* __restrict__ cond_b,
                          const float* __restrict__ cend_w, const float* __restrict__ cend_b,
                          float* __restrict__ cbias, float* __restrict__ cend){
  int blk = blockIdx.x; int m = threadIdx.x;
  if (blk < NLAYERS*NB){
    int l = blk >> 2, b = blk & 3;
    int o = ((m & 1) << 7) + (m >> 1);
    float acc = dil_b[l*256 + o] + cond_b[l*256 + o];
    const float* w = cond_w + ((size_t)l*256 + o)*CONDC;
    const float* cv = cond + b*CONDC;
    for (int c = 0; c < CONDC; ++c) acc += w[c]*cv[c];
    cbias[((size_t)l*NB + b)*256 + m] = acc;
  } else {
    int b = blk - NLAYERS*NB;
    float acc = cend_b[m];
    const float* w = cend_w + (size_t)m*CONDC;
    const float* cv = cond + b*CONDC;
    for (int c = 0; c < CONDC; ++c) acc += w[c]*cv[c];
    cend[b*256 + m] = acc;
  }
}

// ---------------------------------------------------------------------------
// start conv via MFMA, tap-decomposed: out[oc][t] = b[oc] + sum_k Wk @ in[:, t+k]
__global__ __launch_bounds__(BLK) void start_mfma(const float* __restrict__ in,
    const unsigned short* __restrict__ startWb, const float* __restrict__ bias,
    float* __restrict__ xout){
  __shared__ char Bs[80*128];   // [tt:80][c:64] bf16, 16B slots: slot ^= (tt&7)
  const int tid = threadIdx.x;
  const int b = blockIdx.y; const int t0 = blockIdx.x * TILE;
  const int lane = tid & 63;
  const int wave = __builtin_amdgcn_readfirstlane(tid >> 6);
  const int q = lane >> 4, r16 = lane & 15;

  #pragma unroll
  for (int i = 0; i < 5; ++i){
    int j = tid + i*BLK;              // 0..2559 = 32 c-pairs x 80 tt
    int c2 = j / 80, tt = j % 80;
    int c = 2*c2; int gt = t0 + tt;
    float v0 = 0.f, v1 = 0.f;
    if (gt < T_IN && c < INC){
      const float* base = in + ((size_t)(b*INC + c))*T_IN + gt;
      v0 = base[0]; v1 = base[T_IN];
    }
    unsigned u = (unsigned)f2bf(v0) | ((unsigned)f2bf(v1) << 16);
    int slot = c2 >> 2;
    *(unsigned*)(Bs + tt*128 + ((((slot ^ (tt & 7)) << 4)) | ((4*c2) & 15))) = u;
  }
  __syncthreads();

  f32x4 acc[4] = {};
  for (int k = 0; k < 10; ++k){
    const unsigned short* A = startWb + ((size_t)k*128 + wave*16)*64;
    #pragma unroll
    for (int kk = 0; kk < 2; ++kk){
      int k0 = kk*32 + q*8;
      bf16x8 a = *(const bf16x8*)(A + (size_t)r16*64 + k0);
      int slot = k0 >> 3;
      #pragma unroll
      for (int nt = 0; nt < 4; ++nt){
        int t = nt*16 + r16 + k;
        bf16x8 bf = *(const bf16x8*)(Bs + t*128 + ((slot ^ (t & 7)) << 4));
        acc[nt] = __builtin_amdgcn_mfma_f32_16x16x32_bf16(a, bf, acc[nt], 0, 0, 0);
      }
    }
  }
  const float* bb = bias + wave*16;
  #pragma unroll
  for (int nt = 0; nt < 4; ++nt){
    int gt = t0 + nt*16 + r16;
    if (gt < T0LEN){
      #pragma unroll
      for (int rr = 0; rr < 4; ++rr){
        int oc = wave*16 + 4*q + rr;
        xout[(size_t)(b*RES_C + oc)*T_IN + gt] = acc[nt][rr] + bb[4*q + rr];
      }
    }
  }
}

// ---------------------------------------------------------------------------
// Fused MFMA layer, two 32-col tiles per block, software-pipelined (T3/T14):
//  - tile-B raw x loads issued right after tile-A's LDS pack (in flight across
//    all of A's GEMMs);
//  - old-skip values preloaded early per tile -> skip epilogue is a pure write.
// All fragment/swizzle conventions byte-identical to the R6-proven LTILE=32 code.
__global__ __launch_bounds__(BLK) void layer_mfma(
    const float* __restrict__ xin, float* __restrict__ xout, float* __restrict__ skip,
    const unsigned short* __restrict__ dilWb, const unsigned short* __restrict__ skipWb,
    const unsigned short* __restrict__ resWb, const float* __restrict__ cbias,
    const float* __restrict__ skip_b, const float* __restrict__ res_b,
    int layer, int d, int Tin, int Tout, int first, int last){
  __shared__ char BxA[32*512], BxB[32*512];   // [t][k:256] bf16, slot ^= t
  __shared__ char BzA[32*256], BzB[32*256];   // [t][ch:128] bf16, slot ^= (t&15)
  const int tid = threadIdx.x;
  const int b = blockIdx.y; const int t0 = blockIdx.x*64;
  const int lane = tid & 63;
  const int wave = __builtin_amdgcn_readfirstlane(tid >> 6);
  const int q = lane >> 4, r16 = lane & 15;
  const int st = lane & 31;        // stage row (t within tile)
  const int kh = lane >> 5;        // stage k-half
  const int woff = Tout - T_FIN;

  const float* cb = cbias + ((size_t)layer*NB + b)*256 + wave*32;
  const unsigned short* dA = dilWb  + (size_t)layer*256*256 + (size_t)(wave*32)*256;
  const unsigned short* sA = skipWb + (size_t)layer*256*128 + (size_t)(wave*32)*128;
  const unsigned short* rA = resWb  + (size_t)layer*128*128 + (size_t)(wave*16)*128;
  const float* sb = skip_b + layer*256 + wave*32;
  const float* rb = res_b  + layer*RES_C + wave*16;

  float a0A[8], a1A[8], a0B[8], a1B[8];
  float soldA[16], soldB[16];

  // ---- issue tile-A raw x loads
  #pragma unroll
  for (int i = 0; i < 8; ++i){
    int k0 = wave*32 + kh*16 + 2*i;
    int tap = k0 >> 7; int c = k0 & 127;
    int gtt = t0 + st + (tap ? d : 0);
    a0A[i] = 0.f; a1A[i] = 0.f;
    if (gtt < Tin){
      const float* base = xin + ((size_t)(b*RES_C + c))*T_IN + gtt;
      a0A[i] = base[0]; a1A[i] = base[T_IN];
    }
  }
  // ---- issue tile-A old-skip loads (pure-write epilogue later)
  #pragma unroll
  for (int nt = 0; nt < 2; ++nt){
    int gt = t0 + nt*16 + r16; int tw = gt - woff;
    bool ld = (!first) && (gt < Tout) && (tw >= 0);
    #pragma unroll
    for (int mt = 0; mt < 2; ++mt){
      #pragma unroll
      for (int rr = 0; rr < 4; ++rr){
        int m = wave*32 + mt*16 + 4*q + rr;
        soldA[nt*8+mt*4+rr] = ld ? skip[((size_t)(b*SKIPC + m))*T_FIN + tw] : 0.f;
      }
    }
  }

  // ---- pack tile A -> BxA
  #pragma unroll
  for (int i = 0; i < 8; ++i){
    int k0 = wave*32 + kh*16 + 2*i;
    unsigned u = (unsigned)f2bf(a0A[i]) | ((unsigned)f2bf(a1A[i]) << 16);
    int slot = k0 >> 3;
    *(unsigned*)(BxA + st*512 + ((slot ^ st) << 4) + ((2*k0) & 15)) = u;
  }
  __syncthreads();

  // ---- issue tile-B raw x loads (in flight across all of A's compute)
  #pragma unroll
  for (int i = 0; i < 8; ++i){
    int k0 = wave*32 + kh*16 + 2*i;
    int tap = k0 >> 7; int c = k0 & 127;
    int gtt = t0 + 32 + st + (tap ? d : 0);
    a0B[i] = 0.f; a1B[i] = 0.f;
    if (gtt < Tin){
      const float* base = xin + ((size_t)(b*RES_C + c))*T_IN + gtt;
      a0B[i] = base[0]; a1B[i] = base[T_IN];
    }
  }

  // ================= tile A compute =================
  // dil GEMM: M=256 (f/g interleaved), K=256, N=32
  f32x4 acc[2][2] = {};
  for (int kk = 0; kk < 8; ++kk){
    int k0 = kk*32 + q*8;
    bf16x8 w0 = *(const bf16x8*)(dA + (size_t)r16*256 + k0);
    bf16x8 w1 = *(const bf16x8*)(dA + (size_t)(16 + r16)*256 + k0);
    int slot = k0 >> 3;
    #pragma unroll
    for (int nt = 0; nt < 2; ++nt){
      int t = nt*16 + r16;
      bf16x8 bf = *(const bf16x8*)(BxA + t*512 + ((slot ^ t) << 4));
      acc[0][nt] = __builtin_amdgcn_mfma_f32_16x16x32_bf16(w0, bf, acc[0][nt], 0, 0, 0);
      acc[1][nt] = __builtin_amdgcn_mfma_f32_16x16x32_bf16(w1, bf, acc[1][nt], 0, 0, 0);
    }
  }
  // gate -> BzA
  #pragma unroll
  for (int mt = 0; mt < 2; ++mt){
    float bf0 = cb[mt*16 + 4*q + 0];
    float bg0 = cb[mt*16 + 4*q + 1];
    float bf1 = cb[mt*16 + 4*q + 2];
    float bg1 = cb[mt*16 + 4*q + 3];
    int ch0 = wave*16 + mt*8 + 2*q;
    int slot = ch0 >> 3;
    #pragma unroll
    for (int nt = 0; nt < 2; ++nt){
      float z0 = ftanh(acc[mt][nt][0] + bf0) * fsigmoid(acc[mt][nt][1] + bg0);
      float z1 = ftanh(acc[mt][nt][2] + bf1) * fsigmoid(acc[mt][nt][3] + bg1);
      int t = nt*16 + r16;
      unsigned u = (unsigned)f2bf(z0) | ((unsigned)f2bf(z1) << 16);
      *(unsigned*)(BzA + t*256 + ((slot ^ (t & 15)) << 4) + ((2*ch0) & 15)) = u;
    }
  }
  __syncthreads();

  // skip GEMM A: M=256, K=128 (pure write, sold preloaded)
  {
    f32x4 sacc[2][2] = {};
    for (int kk = 0; kk < 4; ++kk){
      int k0 = kk*32 + q*8;
      bf16x8 w0 = *(const bf16x8*)(sA + (size_t)r16*128 + k0);
      bf16x8 w1 = *(const bf16x8*)(sA + (size_t)(16 + r16)*128 + k0);
      int slot = k0 >> 3;
      #pragma unroll
      for (int nt = 0; nt < 2; ++nt){
        int t = nt*16 + r16;
        bf16x8 bf = *(const bf16x8*)(BzA + t*256 + ((slot ^ (t & 15)) << 4));
        sacc[0][nt] = __builtin_amdgcn_mfma_f32_16x16x32_bf16(w0, bf, sacc[0][nt], 0, 0, 0);
        sacc[1][nt] = __builtin_amdgcn_mfma_f32_16x16x32_bf16(w1, bf, sacc[1][nt], 0, 0, 0);
      }
    }
    #pragma unroll
    for (int mt = 0; mt < 2; ++mt){
      #pragma unroll
      for (int nt = 0; nt < 2; ++nt){
        int gt = t0 + nt*16 + r16; int tw = gt - woff;
        if (gt < Tout && tw >= 0){
          #pragma unroll
          for (int rr = 0; rr < 4; ++rr){
            int m = wave*32 + mt*16 + 4*q + rr;
            skip[((size_t)(b*SKIPC + m))*T_FIN + tw] =
                sacc[mt][nt][rr] + sb[mt*16 + 4*q + rr] + soldA[nt*8+mt*4+rr];
          }
        }
      }
    }
  }

  // res GEMM A: M=128, K=128 (skipped on last layer)
  if (!last){
    f32x4 racc[2] = {};
    for (int kk = 0; kk < 4; ++kk){
      int k0 = kk*32 + q*8;
      bf16x8 w0 = *(const bf16x8*)(rA + (size_t)r16*128 + k0);
      int slot = k0 >> 3;
      #pragma unroll
      for (int nt = 0; nt < 2; ++nt){
        int t = nt*16 + r16;
        bf16x8 bf = *(const bf16x8*)(BzA + t*256 + ((slot ^ (t & 15)) << 4));
        racc[nt] = __builtin_amdgcn_mfma_f32_16x16x32_bf16(w0, bf, racc[nt], 0, 0, 0);
      }
    }
    #pragma unroll
    for (int nt = 0; nt < 2; ++nt){
      int gt = t0 + nt*16 + r16;
      if (gt < Tout){
        #pragma unroll
        for (int rr = 0; rr < 4; ++rr){
          int m = wave*16 + 4*q + rr;
          size_t base = ((size_t)(b*RES_C + m))*T_IN;
          xout[base + gt] = racc[nt][rr] + rb[4*q + rr] + xin[base + gt + d];
        }
      }
    }
  }

  // ---- issue tile-B old-skip loads
  #pragma unroll
  for (int nt = 0; nt < 2; ++nt){
    int gt = t0 + 32 + nt*16 + r16; int tw = gt - woff;
    bool ld = (!first) && (gt < Tout) && (tw >= 0);
    #pragma unroll
    for (int mt = 0; mt < 2; ++mt){
      #pragma unroll
      for (int rr = 0; rr < 4; ++rr){
        int m = wave*32 + mt*16 + 4*q + rr;
        soldB[nt*8+mt*4+rr] = ld ? skip[((size_t)(b*SKIPC + m))*T_FIN + tw] : 0.f;
      }
    }
  }

  // ---- pack tile B -> BxB
  #pragma unroll
  for (int i = 0; i < 8; ++i){
    int k0 = wave*32 + kh*16 + 2*i;
    unsigned u = (unsigned)f2bf(a0B[i]) | ((unsigned)f2bf(a1B[i]) << 16);
    int slot = k0 >> 3;
    *(unsigned*)(BxB + st*512 + ((slot ^ st) << 4) + ((2*k0) & 15)) = u;
  }
  __syncthreads();

  // ================= tile B compute =================
  f32x4 accB[2][2] = {};
  for (int kk = 0; kk < 8; ++kk){
    int k0 = kk*32 + q*8;
    bf16x8 w0 = *(const bf16x8*)(dA + (size_t)r16*256 + k0);
    bf16x8 w1 = *(const bf16x8*)(dA + (size_t)(16 + r16)*256 + k0);
    int slot = k0 >> 3;
    #pragma unroll
    for (int nt = 0; nt < 2; ++nt){
      int t = nt*16 + r16;
      bf16x8 bf = *(const bf16x8*)(BxB + t*512 + ((slot ^ t) << 4));
      accB[0][nt] = __builtin_amdgcn_mfma_f32_16x16x32_bf16(w0, bf, accB[0][nt], 0, 0, 0);
      accB[1][nt] = __builtin_amdgcn_mfma_f32_16x16x32_bf16(w1, bf, accB[1][nt], 0, 0, 0);
    }
  }
  #pragma unroll
  for (int mt = 0; mt < 2; ++mt){
    float bf0 = cb[mt*16 + 4*q + 0];
    float bg0 = cb[mt*16 + 4*q + 1];
    float bf1 = cb[mt*16 + 4*q + 2];
    float bg1 = cb[mt*16 + 4*q + 3];
    int ch0 = wave*16 + mt*8 + 2*q;
    int slot = ch0 >> 3;
    #pragma unroll
    for (int nt = 0; nt < 2; ++nt){
      float z0 = ftanh(accB[mt][nt][0] + bf0) * fsigmoid(accB[mt][nt][1] + bg0);
      float z1 = ftanh(accB[mt][nt][2] + bf1) * fsigmoid(accB[mt][nt][3] + bg1);
      int t = nt*16 + r16;
      unsigned u = (unsigned)f2bf(z0) | ((unsigned)f2bf(z1) << 16);
      *(unsigned*)(BzB + t*256 + ((slot ^ (t & 15)) << 4) + ((2*ch0) & 15)) = u;
    }
  }
  __syncthreads();

  {
    f32x4 sacc[2][2] = {};
    for (int kk = 0; kk < 4; ++kk){
      int k0 = kk*32 + q*8;
      bf16x8 w0 = *(const bf16x8*)(sA + (size_t)r16*128 + k0);
      bf16x8 w1 = *(const bf16x8*)(sA + (size_t)(16 + r16)*128 + k0);
      int slot = k0 >> 3;
      #pragma unroll
      for (int nt = 0; nt < 2; ++nt){
        int t = nt*16 + r16;
        bf16x8 bf = *(const bf16x8*)(BzB + t*256 + ((slot ^ (t & 15)) << 4));
        sacc[0][nt] = __builtin_amdgcn_mfma_f32_16x16x32_bf16(w0, bf, sacc[0][nt], 0, 0, 0);
        sacc[1][nt] = __builtin_amdgcn_mfma_f32_16x16x32_bf16(w1, bf, sacc[1][nt], 0, 0, 0);
      }
    }
    #pragma unroll
    for (int mt = 0; mt < 2; ++mt){
      #pragma unroll
      for (int nt = 0; nt < 2; ++nt){
        int gt = t0 + 32 + nt*16 + r16; int tw = gt - woff;
        if (gt < Tout && tw >= 0){
          #pragma unroll
          for (int rr = 0; rr < 4; ++rr){
            int m = wave*32 + mt*16 + 4*q + rr;
            skip[((size_t)(b*SKIPC + m))*T_FIN + tw] =
                sacc[mt][nt][rr] + sb[mt*16 + 4*q + rr] + soldB[nt*8+mt*4+rr];
          }
        }
      }
    }
  }

  if (!last){
    f32x4 racc[2] = {};
    for (int kk = 0; kk < 4; ++kk){
      int k0 = kk*32 + q*8;
      bf16x8 w0 = *(const bf16x8*)(rA + (size_t)r16*128 + k0);
      int slot = k0 >> 3;
      #pragma unroll
      for (int nt = 0; nt < 2; ++nt){
        int t = nt*16 + r16;
        bf16x8 bf = *(const bf16x8*)(BzB + t*256 + ((slot ^ (t & 15)) << 4));
        racc[nt] = __builtin_amdgcn_mfma_f32_16x16x32_bf16(w0, bf, racc[nt], 0, 0, 0);
      }
    }
    #pragma unroll
    for (int nt = 0; nt < 2; ++nt){
      int gt = t0 + 32 + nt*16 + r16;
      if (gt < Tout){
        #pragma unroll
        for (int rr = 0; rr < 4; ++rr){
          int m = wave*16 + 4*q + rr;
          size_t base = ((size_t)(b*RES_C + m))*T_IN;
          xout[base + gt] = racc[nt][rr] + rb[4*q + rr] + xin[base + gt + d];
        }
      }
    }
  }
}

// ---------------------------------------------------------------------------
// final (proven): out = sigmoid(end_b + endW @ tanh(skip + cend)), M=240(pad 256), K=256
__global__ __launch_bounds__(BLK) void final_mfma(const float* __restrict__ skip,
    const float* __restrict__ cend, const unsigned short* __restrict__ endWb,
    const float* __restrict__ end_b, float* __restrict__ out){
  __shared__ char Bs[64*512];   // [t][s:256] bf16, slot ^= (t&31)
  const int tid = threadIdx.x;
  const int b = blockIdx.y; const int t0 = blockIdx.x*TILE;
  const int lane = tid & 63;
  const int wave = __builtin_amdgcn_readfirstlane(tid >> 6);
  const int q = lane >> 4;
  const int r16 = lane & 15;

  {
    const int t = lane;
    const int gt = t0 + t;
    #pragma unroll
    for (int i = 0; i < 32; i += 2){
      int s0 = wave*32 + i;
      float v0 = 0.f, v1 = 0.f;
      if (gt < T_FIN){
        const float* base = skip + ((size_t)(b*SKIPC + s0))*T_FIN + gt;
        v0 = ftanh(base[0]     + cend[b*256 + s0]);
        v1 = ftanh(base[T_FIN] + cend[b*256 + s0 + 1]);
      }
      unsigned u = (unsigned)f2bf(v0) | ((unsigned)f2bf(v1) << 16);
      int slot = s0 >> 3;
      *(unsigned*)(Bs + t*512 + ((slot ^ (t & 31)) << 4) + ((2*s0) & 15)) = u;
    }
  }
  __syncthreads();

  f32x4 acc[2][4] = {};
  const unsigned short* A = endWb + (size_t)(wave*32)*256;
  for (int kk = 0; kk < 8; ++kk){
    int k0 = kk*32 + q*8;
    bf16x8 a0 = *(const bf16x8*)(A + (size_t)r16*256 + k0);
    bf16x8 a1 = *(const bf16x8*)(A + (size_t)(16 + r16)*256 + k0);
    int slot = k0 >> 3;
    #pragma unroll
    for (int nt = 0; nt < 4; ++nt){
      int t = nt*16 + r16;
      bf16x8 bf = *(const bf16x8*)(Bs + t*512 + ((slot ^ (t & 31)) << 4));
      acc[0][nt] = __builtin_amdgcn_mfma_f32_16x16x32_bf16(a0, bf, acc[0][nt], 0, 0, 0);
      acc[1][nt] = __builtin_amdgcn_mfma_f32_16x16x32_bf16(a1, bf, acc[1][nt], 0, 0, 0);
    }
  }
  #pragma unroll
  for (int mt = 0; mt < 2; ++mt){
    #pragma unroll
    for (int nt = 0; nt < 4; ++nt){
      int gt = t0 + nt*16 + r16;
      if (gt < T_FIN){
        #pragma unroll
        for (int rr = 0; rr < 4; ++rr){
          int m = wave*32 + mt*16 + 4*q + rr;
          if (m < OUTC)
            out[((size_t)(b*OUTC + m))*T_FIN + gt] = fsigmoid(acc[mt][nt][rr] + end_b[m]);
        }
      }
    }
  }
}

// ---------------------------------------------------------------------------
extern "C" void kernel_launch(void* const* d_in, const int* in_sizes, int n_in,
                              void* d_out, int out_size, void* d_ws, size_t ws_size,
                              hipStream_t stream){
  const float* input     = (const float*)d_in[0];
  const float* condition = (const float*)d_in[1];
  const float* start_w   = (const float*)d_in[2];
  const float* start_b   = (const float*)d_in[3];
  const float* dil_w     = (const float*)d_in[4];
  const float* dil_b     = (const float*)d_in[5];
  const float* cond_w    = (const float*)d_in[6];
  const float* cond_b    = (const float*)d_in[7];
  const float* res_w     = (const float*)d_in[8];
  const float* res_b     = (const float*)d_in[9];
  const float* skip_w    = (const float*)d_in[10];
  const float* skip_b    = (const float*)d_in[11];
  const float* end_w     = (const float*)d_in[12];
  const float* end_b     = (const float*)d_in[13];
  const float* cend_w    = (const float*)d_in[14];
  const float* cend_b    = (const float*)d_in[15];
  float* out = (float*)d_out;

  char* ws = (char*)d_ws;
  size_t off = 0;
  auto carve = [&](size_t bytes) -> char* {
    char* p = ws + off; off = (off + bytes + 255) & ~(size_t)255; return p;
  };
  float* xA   = (float*)carve((size_t)NB*RES_C*T_IN*4);
  float* xB   = (float*)carve((size_t)NB*RES_C*T_IN*4);
  float* skip = (float*)carve((size_t)NB*SKIPC*T_FIN*4);
  unsigned short* dilWb   = (unsigned short*)carve((size_t)NDIL*2);
  unsigned short* skipWb  = (unsigned short*)carve((size_t)NSKP*2);
  unsigned short* resWb   = (unsigned short*)carve((size_t)NRES*2);
  unsigned short* endWb   = (unsigned short*)carve((size_t)NEND*2);
  unsigned short* startWb = (unsigned short*)carve((size_t)NSTART*2);
  float* cbias = (float*)carve((size_t)NLAYERS*NB*256*4);
  float* cend  = (float*)carve((size_t)NB*256*4);

  prep_weights<<<2048, 256, 0, stream>>>(dil_w, skip_w, res_w, end_w, start_w,
                                         dilWb, skipWb, resWb, endWb, startWb);
  prep_bias<<<NLAYERS*NB + NB, 256, 0, stream>>>(condition, dil_b, cond_w, cond_b,
                                                 cend_w, cend_b, cbias, cend);

  {
    dim3 grid((T0LEN + TILE - 1)/TILE, NB);
    start_mfma<<<grid, BLK, 0, stream>>>(input, startWb, start_b, xA);
  }

  int dils[NLAYERS]; int n = 0;
  for (int bb = 0; bb < 2; ++bb){ int nn = (bb==0) ? 10 : 9; for (int k = 0; k < nn; ++k) dils[n++] = 1<<k; }

  float* xin = xA; float* xo = xB;
  int Tin = T0LEN;
  for (int i = 0; i < NLAYERS; ++i){
    int d = dils[i]; int Tout = Tin - d;
    dim3 grid((Tout + 63)/64, NB);
    layer_mfma<<<grid, BLK, 0, stream>>>(xin, xo, skip, dilWb, skipWb, resWb, cbias,
                                         skip_b, res_b, i, d, Tin, Tout,
                                         (i==0)?1:0, (i==NLAYERS-1)?1:0);
    float* tmp = xin; xin = xo; xo = tmp;
    Tin = Tout;
  }

  {
    dim3 grid((T_FIN + TILE - 1)/TILE, NB);
    final_mfma<<<grid, BLK, 0, stream>>>(skip, cend, endWb, end_b, out);
  }
}

// Round 9
// 551.826 us; speedup vs baseline: 1.8615x; 1.8437x over previous
//
#include <hip/hip_runtime.h>
#include <cstdint>
#include <cstddef>

#define NLAYERS 19
#define NB 4
#define RES_C 128
#define DIL2 256
#define SKIPC 256
#define INC 60
#define CONDC 80
#define OUTC 240
#define T_IN 6144
#define T0LEN 6135   // after start conv (K=10, VALID)
#define T_FIN 4601
#define TILE 64      // start/final tile
#define LTILE 32     // layer tile (R6-proven geometry)
#define BLK 512
#define ZROWS 4608   // window rows per (layer,batch), padded to 72*64

#define NDIL (NLAYERS*256*256)
#define NSKP (NLAYERS*256*128)
#define NRES (NLAYERS*128*128)
#define NEND (256*256)
#define NSTART (10*128*64)

typedef short bf16x8 __attribute__((ext_vector_type(8)));
typedef float f32x4 __attribute__((ext_vector_type(4)));
typedef unsigned uint32x2 __attribute__((ext_vector_type(2)));

#if __has_builtin(__builtin_amdgcn_exp2f)
#define EXP2F(x) __builtin_amdgcn_exp2f(x)
#else
#define EXP2F(x) exp2f(x)
#endif
#if __has_builtin(__builtin_amdgcn_rcpf)
#define RCPF(x) __builtin_amdgcn_rcpf(x)
#else
#define RCPF(x) (1.0f/(x))
#endif

__device__ __forceinline__ float fexp(float x){ return EXP2F(x * 1.4426950408889634f); }
__device__ __forceinline__ float fsigmoid(float x){ return RCPF(1.0f + fexp(-x)); }
__device__ __forceinline__ float ftanh(float x){ return 1.0f - 2.0f * RCPF(1.0f + fexp(2.0f*x)); }

__device__ __forceinline__ unsigned short f2bf(float f){
  unsigned u = __builtin_bit_cast(unsigned, f);
  u = u + 0x7FFFu + ((u >> 16) & 1u);   // RNE (finite values only)
  return (unsigned short)(u >> 16);
}

// ---------------------------------------------------------------------------
// Pack weights to bf16 (R5-proven).
__global__ void prep_weights(const float* __restrict__ dil_w, const float* __restrict__ skip_w,
                             const float* __restrict__ res_w, const float* __restrict__ end_w,
                             const float* __restrict__ start_w,
                             unsigned short* __restrict__ dilWb, unsigned short* __restrict__ skipWb,
                             unsigned short* __restrict__ resWb, unsigned short* __restrict__ endWb,
                             unsigned short* __restrict__ startWb){
  const int total = NDIL + NSKP + NRES + NEND + NSTART;
  for (int idx = blockIdx.x*256 + threadIdx.x; idx < total; idx += gridDim.x*256){
    if (idx < NDIL){
      int l = idx >> 16; int rem = idx & 65535; int m = rem >> 8; int k = rem & 255;
      int o = ((m & 1) << 7) + (m >> 1); int c = k & 127; int tap = k >> 7;
      dilWb[idx] = f2bf(dil_w[(((size_t)l*256 + o)*128 + c)*2 + tap]);
    } else if (idx < NDIL + NSKP){
      int j = idx - NDIL;
      skipWb[j] = f2bf(skip_w[j]);
    } else if (idx < NDIL + NSKP + NRES){
      int j = idx - NDIL - NSKP;
      resWb[j] = f2bf(res_w[j]);
    } else if (idx < NDIL + NSKP + NRES + NEND){
      int j = idx - NDIL - NSKP - NRES;
      int m = j >> 8; int k = j & 255;
      endWb[j] = (m < OUTC) ? f2bf(end_w[(size_t)m*256 + k]) : 0;
    } else {
      int j = idx - NDIL - NSKP - NRES - NEND;
      int k = j >> 13; int rem = j & 8191; int oc = rem >> 6; int c = rem & 63;
      startWb[j] = (c < INC) ? f2bf(start_w[((size_t)oc*INC + c)*10 + k]) : 0;
    }
  }
}

// ---------------------------------------------------------------------------
// cbias[l][b][m] = dil_b[o(m)] + cond_b[l][o(m)] + sum_c cond_w[l][o(m)][c]*cond[b][c]
// sbc[b][s]     = cend_b[s] + sum_c cend_w[s][c]*cond[b][c] + sum_l skip_b[l][s]
__global__ void prep_bias(const float* __restrict__ cond, const float* __restrict__ dil_b,
                          const float* __restrict__ cond_w, const float* __restrict__ cond_b,
                          const float* __restrict__ cend_w, const float* __restrict__ cend_b,
                          const float* __restrict__ skip_b,
                          float* __restrict__ cbias, float* __restrict__ sbc){
  int blk = blockIdx.x; int m = threadIdx.x;
  if (blk < NLAYERS*NB){
    int l = blk >> 2, b = blk & 3;
    int o = ((m & 1) << 7) + (m >> 1);
    float acc = dil_b[l*256 + o] + cond_b[l*256 + o];
    const float* w = cond_w + ((size_t)l*256 + o)*CONDC;
    const float* cv = cond + b*CONDC;
    for (int c = 0; c < CONDC; ++c) acc += w[c]*cv[c];
    cbias[((size_t)l*NB + b)*256 + m] = acc;
  } else {
    int b = blk - NLAYERS*NB;
    float acc = cend_b[m];
    const float* w = cend_w + (size_t)m*CONDC;
    const float* cv = cond + b*CONDC;
    for (int c = 0; c < CONDC; ++c) acc += w[c]*cv[c];
    for (int l = 0; l < NLAYERS; ++l) acc += skip_b[l*256 + m];
    sbc[b*256 + m] = acc;
  }
}

// ---------------------------------------------------------------------------
// start conv via MFMA (R5-proven)
__global__ __launch_bounds__(BLK) void start_mfma(const float* __restrict__ in,
    const unsigned short* __restrict__ startWb, const float* __restrict__ bias,
    float* __restrict__ xout){
  __shared__ char Bs[80*128];   // [tt:80][c:64] bf16, slot ^= (tt&7)
  const int tid = threadIdx.x;
  const int b = blockIdx.y; const int t0 = blockIdx.x * TILE;
  const int lane = tid & 63;
  const int wave = __builtin_amdgcn_readfirstlane(tid >> 6);
  const int q = lane >> 4, r16 = lane & 15;

  #pragma unroll
  for (int i = 0; i < 5; ++i){
    int j = tid + i*BLK;              // 0..2559 = 32 c-pairs x 80 tt
    int c2 = j / 80, tt = j % 80;
    int c = 2*c2; int gt = t0 + tt;
    float v0 = 0.f, v1 = 0.f;
    if (gt < T_IN && c < INC){
      const float* base = in + ((size_t)(b*INC + c))*T_IN + gt;
      v0 = base[0]; v1 = base[T_IN];
    }
    unsigned u = (unsigned)f2bf(v0) | ((unsigned)f2bf(v1) << 16);
    int slot = c2 >> 2;
    *(unsigned*)(Bs + tt*128 + ((((slot ^ (tt & 7)) << 4)) | ((4*c2) & 15))) = u;
  }
  __syncthreads();

  f32x4 acc[4] = {};
  for (int k = 0; k < 10; ++k){
    const unsigned short* A = startWb + ((size_t)k*128 + wave*16)*64;
    #pragma unroll
    for (int kk = 0; kk < 2; ++kk){
      int k0 = kk*32 + q*8;
      bf16x8 a = *(const bf16x8*)(A + (size_t)r16*64 + k0);
      int slot = k0 >> 3;
      #pragma unroll
      for (int nt = 0; nt < 4; ++nt){
        int t = nt*16 + r16 + k;
        bf16x8 bf = *(const bf16x8*)(Bs + t*128 + ((slot ^ (t & 7)) << 4));
        acc[nt] = __builtin_amdgcn_mfma_f32_16x16x32_bf16(a, bf, acc[nt], 0, 0, 0);
      }
    }
  }
  const float* bb = bias + wave*16;
  #pragma unroll
  for (int nt = 0; nt < 4; ++nt){
    int gt = t0 + nt*16 + r16;
    if (gt < T0LEN){
      #pragma unroll
      for (int rr = 0; rr < 4; ++rr){
        int oc = wave*16 + 4*q + rr;
        xout[(size_t)(b*RES_C + oc)*T_IN + gt] = acc[nt][rr] + bb[4*q + rr];
      }
    }
  }
}

// ---------------------------------------------------------------------------
// Fused MFMA layer (R6-proven LTILE=32 geometry): dilated GEMM + gate -> Bz,
// z flushed coalesced to batch-indexed zbuf[l][b][window-row][128] (bf16),
// then res GEMM. Skip GEMM deferred to final kernel.
__global__ __launch_bounds__(BLK) void layer_mfma(
    const float* __restrict__ xin, float* __restrict__ xout,
    unsigned short* __restrict__ zl,      // zbuf + l*NB*ZROWS*128
    const unsigned short* __restrict__ dilWb, const unsigned short* __restrict__ resWb,
    const float* __restrict__ cbias, const float* __restrict__ res_b,
    int layer, int d, int Tin, int Tout, int woff, int last){
  __shared__ char Bx[LTILE*512];   // [t][k:256] bf16, slot ^= (t&31)
  __shared__ char Bz[LTILE*256];   // [t][ch:128] bf16, slot ^= (t&15)
  const int tid = threadIdx.x;
  const int b = blockIdx.y; const int t0 = blockIdx.x*LTILE;
  const int lane = tid & 63;
  const int wave = __builtin_amdgcn_readfirstlane(tid >> 6);
  const int q = lane >> 4;
  const int r16 = lane & 15;

  // ---- stage Bx: k<128 = x[t] ch k ; k>=128 = x[t+d] ch k-128
  {
    const int t = lane & 31;
    const int kh = lane >> 5;       // 0/1
    const int gt = t0 + t;
    #pragma unroll
    for (int i = 0; i < 16; i += 2){
      int k0 = wave*32 + kh*16 + i;
      int tap = k0 >> 7; int c = k0 & 127;
      int gtt = gt + (tap ? d : 0);
      float v0 = 0.f, v1 = 0.f;
      if (gtt < Tin){
        const float* base = xin + ((size_t)(b*RES_C + c))*T_IN + gtt;
        v0 = base[0]; v1 = base[T_IN];
      }
      unsigned u = (unsigned)f2bf(v0) | ((unsigned)f2bf(v1) << 16);
      int slot = k0 >> 3;
      *(unsigned*)(Bx + t*512 + ((slot ^ (t & 31)) << 4) + ((2*k0) & 15)) = u;
    }
  }
  __syncthreads();

  // ---- dilated GEMM: M=256 (f/g interleaved), K=256, N=32. wave owns 32 rows.
  f32x4 acc[2][2] = {};
  {
    const unsigned short* A = dilWb + (size_t)layer*256*256 + (size_t)(wave*32)*256;
    for (int kk = 0; kk < 8; ++kk){
      int k0 = kk*32 + q*8;
      bf16x8 a0 = *(const bf16x8*)(A + (size_t)r16*256 + k0);
      bf16x8 a1 = *(const bf16x8*)(A + (size_t)(16 + r16)*256 + k0);
      int slot = k0 >> 3;
      #pragma unroll
      for (int nt = 0; nt < 2; ++nt){
        int t = nt*16 + r16;
        bf16x8 bf = *(const bf16x8*)(Bx + t*512 + ((slot ^ (t & 31)) << 4));
        acc[0][nt] = __builtin_amdgcn_mfma_f32_16x16x32_bf16(a0, bf, acc[0][nt], 0, 0, 0);
        acc[1][nt] = __builtin_amdgcn_mfma_f32_16x16x32_bf16(a1, bf, acc[1][nt], 0, 0, 0);
      }
    }
  }

  // ---- gate + write z to Bz (rows 4q+r hold f,g,f,g of channels 2q,2q+1)
  {
    const float* cb = cbias + ((size_t)layer*NB + b)*256 + wave*32;
    #pragma unroll
    for (int mt = 0; mt < 2; ++mt){
      float bf0 = cb[mt*16 + 4*q + 0];
      float bg0 = cb[mt*16 + 4*q + 1];
      float bf1 = cb[mt*16 + 4*q + 2];
      float bg1 = cb[mt*16 + 4*q + 3];
      int ch0 = wave*16 + mt*8 + 2*q;
      int slot = ch0 >> 3;
      #pragma unroll
      for (int nt = 0; nt < 2; ++nt){
        float z0 = ftanh(acc[mt][nt][0] + bf0) * fsigmoid(acc[mt][nt][1] + bg0);
        float z1 = ftanh(acc[mt][nt][2] + bf1) * fsigmoid(acc[mt][nt][3] + bg1);
        int t = nt*16 + r16;
        unsigned u = (unsigned)f2bf(z0) | ((unsigned)f2bf(z1) << 16);
        *(unsigned*)(Bz + t*256 + ((slot ^ (t & 15)) << 4) + ((2*ch0) & 15)) = u;
      }
    }
  }
  __syncthreads();

  // ---- z-flush: Bz -> zbuf[l][b][windex][128], coalesced rows (256B segments)
  {
    unsigned short* zgb = zl + (size_t)b*ZROWS*128;
    #pragma unroll
    for (int i = 0; i < 4; ++i){
      int j = tid + i*BLK;            // 32 rows x 64 u32
      int row = j >> 6, cu = j & 63;
      int gt = t0 + row;
      int windex = gt - woff;
      if (gt < Tout && windex >= 0){
        int slot = cu >> 2;
        unsigned u = *(const unsigned*)(Bz + row*256 + (((slot ^ (row & 15)) << 4) | ((4*cu) & 15)));
        *(unsigned*)(zgb + (size_t)windex*128 + 2*cu) = u;
      }
    }
  }

  // ---- res GEMM: M=128, K=128. wave owns 16 rows. (skipped on last layer)
  if (!last){
    f32x4 racc[2] = {};
    const unsigned short* A = resWb + (size_t)layer*128*128 + (size_t)(wave*16)*128;
    for (int kk = 0; kk < 4; ++kk){
      int k0 = kk*32 + q*8;
      bf16x8 a0 = *(const bf16x8*)(A + (size_t)r16*128 + k0);
      int slot = k0 >> 3;
      #pragma unroll
      for (int nt = 0; nt < 2; ++nt){
        int t = nt*16 + r16;
        bf16x8 bf = *(const bf16x8*)(Bz + t*256 + ((slot ^ (t & 15)) << 4));
        racc[nt] = __builtin_amdgcn_mfma_f32_16x16x32_bf16(a0, bf, racc[nt], 0, 0, 0);
      }
    }
    const float* rb = res_b + layer*RES_C + wave*16;
    #pragma unroll
    for (int nt = 0; nt < 2; ++nt){
      int gt = t0 + nt*16 + r16;
      if (gt < Tout){
        #pragma unroll
        for (int rr = 0; rr < 4; ++rr){
          int m = wave*16 + 4*q + rr;
          size_t base = ((size_t)(b*RES_C + m))*T_IN;
          xout[base + gt] = racc[nt][rr] + rb[4*q + rr] + xin[base + gt + d];
        }
      }
    }
  }
}

// ---------------------------------------------------------------------------
// final: skip_sum = sum_l skipW[l] @ z_l (z batch-indexed, window-aligned),
// then tanh(skip_sum + sbc) -> Bs, then out = sigmoid(end_b + endW @ Bs).
__global__ __launch_bounds__(BLK) void final_mfma(
    const unsigned short* __restrict__ zbuf,
    const unsigned short* __restrict__ skipWb, const unsigned short* __restrict__ endWb,
    const float* __restrict__ sbc, const float* __restrict__ end_b,
    float* __restrict__ out){
  __shared__ char BzP[2][64*256];   // z tile double-buffer, slot ^= (t&15)
  __shared__ char Bs[64*512];       // tanh(skip) tile [t][s:256], slot ^= (t&31)
  const int tid = threadIdx.x;
  const int b = blockIdx.y; const int t0 = blockIdx.x*TILE;
  const int lane = tid & 63;
  const int wave = __builtin_amdgcn_readfirstlane(tid >> 6);
  const int q = lane >> 4, r16 = lane & 15;

  auto stageZ = [&](int l, int buf){
    const unsigned* zsrc = (const unsigned*)(zbuf + (((size_t)l*NB + b)*ZROWS + t0)*128);
    char* dst = BzP[buf];
    #pragma unroll
    for (int i = 0; i < 8; ++i){
      int j = tid + i*BLK;          // 64 rows x 64 u32
      int row = j >> 6, cu = j & 63;
      unsigned v = zsrc[(size_t)row*64 + cu];
      int slot = cu >> 2;
      *(unsigned*)(dst + row*256 + (((slot ^ (row & 15)) << 4) | ((4*cu) & 15))) = v;
    }
  };

  stageZ(0, 0);
  __syncthreads();

  f32x4 sacc[2][4] = {};
  for (int l = 0; l < NLAYERS; ++l){
    if (l + 1 < NLAYERS) stageZ(l + 1, (l + 1) & 1);
    const unsigned short* A = skipWb + ((size_t)l*256 + wave*32)*128;
    const char* Bb = BzP[l & 1];
    for (int kk = 0; kk < 4; ++kk){
      int k0 = kk*32 + q*8;
      bf16x8 a0 = *(const bf16x8*)(A + (size_t)r16*128 + k0);
      bf16x8 a1 = *(const bf16x8*)(A + (size_t)(16 + r16)*128 + k0);
      int slot = k0 >> 3;
      #pragma unroll
      for (int nt = 0; nt < 4; ++nt){
        int t = nt*16 + r16;
        bf16x8 bf = *(const bf16x8*)(Bb + t*256 + ((slot ^ (t & 15)) << 4));
        sacc[0][nt] = __builtin_amdgcn_mfma_f32_16x16x32_bf16(a0, bf, sacc[0][nt], 0, 0, 0);
        sacc[1][nt] = __builtin_amdgcn_mfma_f32_16x16x32_bf16(a1, bf, sacc[1][nt], 0, 0, 0);
      }
    }
    __syncthreads();
  }

  // tanh(skip_sum + sbc) -> Bs
  {
    const float* sb = sbc + b*256 + wave*32;
    #pragma unroll
    for (int mt = 0; mt < 2; ++mt){
      #pragma unroll
      for (int nt = 0; nt < 4; ++nt){
        int t = nt*16 + r16;
        float v0 = ftanh(sacc[mt][nt][0] + sb[mt*16 + 4*q + 0]);
        float v1 = ftanh(sacc[mt][nt][1] + sb[mt*16 + 4*q + 1]);
        float v2 = ftanh(sacc[mt][nt][2] + sb[mt*16 + 4*q + 2]);
        float v3 = ftanh(sacc[mt][nt][3] + sb[mt*16 + 4*q + 3]);
        uint32x2 u;
        u.x = (unsigned)f2bf(v0) | ((unsigned)f2bf(v1) << 16);
        u.y = (unsigned)f2bf(v2) | ((unsigned)f2bf(v3) << 16);
        int m0 = wave*32 + mt*16 + 4*q;     // byte offset 2*m0 (8B aligned)
        int slot = (2*m0) >> 4;
        *(uint32x2*)(Bs + t*512 + (((slot ^ (t & 31)) << 4) | ((2*m0) & 15))) = u;
      }
    }
  }
  __syncthreads();

  // end GEMM: M=256(240 used), K=256
  f32x4 eacc[2][4] = {};
  const unsigned short* A = endWb + (size_t)(wave*32)*256;
  for (int kk = 0; kk < 8; ++kk){
    int k0 = kk*32 + q*8;
    bf16x8 a0 = *(const bf16x8*)(A + (size_t)r16*256 + k0);
    bf16x8 a1 = *(const bf16x8*)(A + (size_t)(16 + r16)*256 + k0);
    int slot = k0 >> 3;
    #pragma unroll
    for (int nt = 0; nt < 4; ++nt){
      int t = nt*16 + r16;
      bf16x8 bf = *(const bf16x8*)(Bs + t*512 + ((slot ^ (t & 31)) << 4));
      eacc[0][nt] = __builtin_amdgcn_mfma_f32_16x16x32_bf16(a0, bf, eacc[0][nt], 0, 0, 0);
      eacc[1][nt] = __builtin_amdgcn_mfma_f32_16x16x32_bf16(a1, bf, eacc[1][nt], 0, 0, 0);
    }
  }
  #pragma unroll
  for (int mt = 0; mt < 2; ++mt){
    #pragma unroll
    for (int nt = 0; nt < 4; ++nt){
      int gt = t0 + nt*16 + r16;
      if (gt < T_FIN){
        #pragma unroll
        for (int rr = 0; rr < 4; ++rr){
          int m = wave*32 + mt*16 + 4*q + rr;
          if (m < OUTC)
            out[((size_t)(b*OUTC + m))*T_FIN + gt] = fsigmoid(eacc[mt][nt][rr] + end_b[m]);
        }
      }
    }
  }
}

// ---------------------------------------------------------------------------
extern "C" void kernel_launch(void* const* d_in, const int* in_sizes, int n_in,
                              void* d_out, int out_size, void* d_ws, size_t ws_size,
                              hipStream_t stream){
  const float* input     = (const float*)d_in[0];
  const float* condition = (const float*)d_in[1];
  const float* start_w   = (const float*)d_in[2];
  const float* start_b   = (const float*)d_in[3];
  const float* dil_w     = (const float*)d_in[4];
  const float* dil_b     = (const float*)d_in[5];
  const float* cond_w    = (const float*)d_in[6];
  const float* cond_b    = (const float*)d_in[7];
  const float* res_w     = (const float*)d_in[8];
  const float* res_b     = (const float*)d_in[9];
  const float* skip_w    = (const float*)d_in[10];
  const float* skip_b    = (const float*)d_in[11];
  const float* end_w     = (const float*)d_in[12];
  const float* end_b     = (const float*)d_in[13];
  const float* cend_w    = (const float*)d_in[14];
  const float* cend_b    = (const float*)d_in[15];
  float* out = (float*)d_out;

  // ws = 256 MiB (measured R5/R6 fill). Total here ~133 MiB.
  // R3/R4 bug (found R8 post-mortem): zbuf lacked the batch dimension ->
  // all 4 blockIdx.y raced on the same rows. Fixed: zbuf[l][b][row][128].
  char* ws = (char*)d_ws;
  size_t off = 0;
  auto carve = [&](size_t bytes) -> char* {
    char* p = ws + off; off = (off + bytes + 255) & ~(size_t)255; return p;
  };
  float* xA            = (float*)carve((size_t)NB*RES_C*T_IN*4);
  float* xB            = (float*)carve((size_t)NB*RES_C*T_IN*4);
  unsigned short* zbuf = (unsigned short*)carve((size_t)NLAYERS*NB*ZROWS*128*2);
  unsigned short* dilWb   = (unsigned short*)carve((size_t)NDIL*2);
  unsigned short* skipWb  = (unsigned short*)carve((size_t)NSKP*2);
  unsigned short* resWb   = (unsigned short*)carve((size_t)NRES*2);
  unsigned short* endWb   = (unsigned short*)carve((size_t)NEND*2);
  unsigned short* startWb = (unsigned short*)carve((size_t)NSTART*2);
  float* cbias = (float*)carve((size_t)NLAYERS*NB*256*4);
  float* sbc   = (float*)carve((size_t)NB*256*4);

  prep_weights<<<2048, 256, 0, stream>>>(dil_w, skip_w, res_w, end_w, start_w,
                                         dilWb, skipWb, resWb, endWb, startWb);
  prep_bias<<<NLAYERS*NB + NB, 256, 0, stream>>>(condition, dil_b, cond_w, cond_b,
                                                 cend_w, cend_b, skip_b, cbias, sbc);

  {
    dim3 grid((T0LEN + TILE - 1)/TILE, NB);
    start_mfma<<<grid, BLK, 0, stream>>>(input, startWb, start_b, xA);
  }

  int dils[NLAYERS]; int n = 0;
  for (int bb = 0; bb < 2; ++bb){ int nn = (bb==0) ? 10 : 9; for (int k = 0; k < nn; ++k) dils[n++] = 1<<k; }

  float* xin = xA; float* xo = xB;
  int Tin = T0LEN;
  for (int i = 0; i < NLAYERS; ++i){
    int d = dils[i]; int Tout = Tin - d;
    dim3 grid((Tout + LTILE - 1)/LTILE, NB);
    unsigned short* zl = zbuf + (size_t)i*NB*ZROWS*128;
    layer_mfma<<<grid, BLK, 0, stream>>>(xin, xo, zl, dilWb, resWb, cbias, res_b,
                                         i, d, Tin, Tout, Tout - T_FIN,
                                         (i==NLAYERS-1)?1:0);
    float* tmp = xin; xin = xo; xo = tmp;
    Tin = Tout;
  }

  {
    dim3 grid((T_FIN + TILE - 1)/TILE, NB);
    final_mfma<<<grid, BLK, 0, stream>>>(zbuf, skipWb, endWb, sbc, end_b, out);
  }
}